// Round 4
// baseline (364.705 us; speedup 1.0000x reference)
//
#include <hip/hip_runtime.h>
#include <cstddef>

namespace {
constexpr int Z    = 4;
constexpr int N    = 256;
constexpr int CIN  = 32;
constexpr int COUT = 32;
constexpr int HID  = 64;
constexpr int OC   = COUT * CIN;  // 1024
constexpr int NC   = N * COUT;    // 8192
}

typedef float f4 __attribute__((ext_vector_type(4)));  // nt-store-capable float4

// ---------------------------------------------------------------------------
// Kernel 1: one block per (z, b), fused M + H + GEMM (R3 structure verbatim),
// but the epilogue writes T[zrel][b][a][i] — a contiguous 32 KB slice per
// block, nontemporal — instead of scattering 256 x 128 B lines across the
// 33.5 MB output (R3: 17x write amplification + W2 L2-thrash -> 278 MiB
// fetch). Contiguous exclusive slices stream out without L2 thrash.
// ---------------------------------------------------------------------------
__global__ __launch_bounds__(256, 2) void fused_pair_T(
    const float* __restrict__ features,
    const float* __restrict__ geometry,
    const float* __restrict__ W1,
    const float* __restrict__ b1,
    const float* __restrict__ W2,
    const float* __restrict__ b2,
    float* __restrict__ Tws,
    int z0)
{
    __shared__ __align__(16) float Ml[COUT * HID];   // 8 KB, M[i][h]
    __shared__ __align__(16) float stage[128 * 36];  // 18 KB
    __shared__ __align__(16) float geo[N * 3];       // 3 KB
    __shared__ __align__(16) float w1l[4 * HID];     // 1 KB
    __shared__ __align__(16) float fl[CIN];
    __shared__ float bfl[COUT];

    const int blk  = blockIdx.x;
    const int zrel = blk >> 8;
    const int z    = z0 + zrel;
    const int b    = blk & 255;
    const int t    = threadIdx.x;

    // ---- cooperative loads ----
    if (t < 192)
        reinterpret_cast<float4*>(geo)[t] =
            reinterpret_cast<const float4*>(geometry + (size_t)z * N * 3)[t];
    if (t < HID) {
        w1l[t]            = W1[t];
        w1l[HID + t]      = W1[HID + t];
        w1l[2 * HID + t]  = W1[2 * HID + t];
        w1l[3 * HID + t]  = b1[t];
    }
    if (t < CIN) fl[t] = features[((size_t)z * N + b) * CIN + t];
    __syncthreads();

    // ---- M phase: M[i][h] = sum_j W2[h][i*32+j] * f[j]; 8 dots/thread ----
    {
        float4 f4r[8];
#pragma unroll
        for (int q = 0; q < 8; ++q) f4r[q] = *reinterpret_cast<const float4*>(&fl[q * 4]);
        const int hh = t & 63;
        const int i0 = t >> 6;           // 0..3
#pragma unroll
        for (int p = 0; p < 8; ++p) {
            const int i = i0 + 4 * p;    // 0..31
            const float4* w2r = reinterpret_cast<const float4*>(
                W2 + (size_t)hh * OC + i * CIN);
            float v = 0.f;
#pragma unroll
            for (int q = 0; q < 8; ++q) {
                const float4 w = w2r[q];
                const float4 f = f4r[q];
                v += w.x * f.x + w.y * f.y + w.z * f.z + w.w * f.w;
            }
            Ml[i * HID + hh] = v;
        }
        if (t < COUT) {
            const float4* b2r = reinterpret_cast<const float4*>(b2 + t * CIN);
            float v = 0.f;
#pragma unroll
            for (int q = 0; q < 8; ++q) {
                const float4 bb = b2r[q];
                const float4 f  = f4r[q];
                v += bb.x * f.x + bb.y * f.y + bb.z * f.z + bb.w * f.w;
            }
            bfl[t] = v;
        }
    }

    const int a_thr = t & 31;
    const int i_thr = t >> 5;            // 0..7
    __syncthreads();

    const float gbx = geo[b * 3 + 0], gby = geo[b * 3 + 1], gbz = geo[b * 3 + 2];
    float dx[8], dy[8], dz[8];
#pragma unroll
    for (int u = 0; u < 8; ++u) {
        const int a = a_thr + 32 * u;
        dx[u] = gbx - geo[a * 3 + 0];
        dy[u] = gby - geo[a * 3 + 1];
        dz[u] = gbz - geo[a * 3 + 2];
    }

    float acc[8][4];
#pragma unroll
    for (int u = 0; u < 8; ++u)
#pragma unroll
        for (int v = 0; v < 4; ++v) acc[u][v] = bfl[i_thr * 4 + v];

    // ---- main loop: build H in registers per k-chunk, FMA against M ----
#pragma unroll
    for (int k4 = 0; k4 < 16; ++k4) {
        const float4 w1x = *reinterpret_cast<const float4*>(&w1l[k4 * 4]);
        const float4 w1y = *reinterpret_cast<const float4*>(&w1l[HID + k4 * 4]);
        const float4 w1z = *reinterpret_cast<const float4*>(&w1l[2 * HID + k4 * 4]);
        const float4 b1v = *reinterpret_cast<const float4*>(&w1l[3 * HID + k4 * 4]);
        float4 m[4];
#pragma unroll
        for (int v = 0; v < 4; ++v)
            m[v] = *reinterpret_cast<const float4*>(&Ml[(i_thr * 4 + v) * HID + k4 * 4]);
#pragma unroll
        for (int u = 0; u < 8; ++u) {
            float4 h;
            h.x = fmaxf(fmaf(dx[u], w1x.x, fmaf(dy[u], w1y.x, fmaf(dz[u], w1z.x, b1v.x))), 0.f);
            h.y = fmaxf(fmaf(dx[u], w1x.y, fmaf(dy[u], w1y.y, fmaf(dz[u], w1z.y, b1v.y))), 0.f);
            h.z = fmaxf(fmaf(dx[u], w1x.z, fmaf(dy[u], w1y.z, fmaf(dz[u], w1z.z, b1v.z))), 0.f);
            h.w = fmaxf(fmaf(dx[u], w1x.w, fmaf(dy[u], w1y.w, fmaf(dz[u], w1z.w, b1v.w))), 0.f);
#pragma unroll
            for (int v = 0; v < 4; ++v)
                acc[u][v] += h.x * m[v].x + h.y * m[v].y + h.z * m[v].z + h.w * m[v].w;
        }
    }

    // ---- epilogue: T[zrel][b][a][i], contiguous 32 KB per block, nt stores
    float* Tb = Tws + ((size_t)zrel * N + b) * NC;
#pragma unroll
    for (int half = 0; half < 2; ++half) {
        __syncthreads();
#pragma unroll
        for (int u = 0; u < 4; ++u) {
            const int uu = half * 4 + u;
            float4 o;
            o.x = acc[uu][0]; o.y = acc[uu][1]; o.z = acc[uu][2]; o.w = acc[uu][3];
            *reinterpret_cast<float4*>(&stage[(a_thr + 32 * u) * 36 + i_thr * 4]) = o;
        }
        __syncthreads();
#pragma unroll
        for (int r = 0; r < 4; ++r) {
            const int c = r * 256 + t;           // 0..1023
            const f4 val = *reinterpret_cast<const f4*>(
                &stage[(c >> 3) * 36 + (c & 7) * 4]);
            // (half*128 + a_loc)*32 + i4*4  ==  half*4096 + c*4  (contiguous)
            __builtin_nontemporal_store(
                val, reinterpret_cast<f4*>(&Tb[half * 4096 + c * 4]));
        }
    }
}

// ---------------------------------------------------------------------------
// Kernel 2: tiled transpose T[z][b][a][i] -> out[z][a][b][i].
// 16a x 16b cell tiles (cell = 32 floats). Reads: 2 KB-contiguous runs per b;
// writes: 2 KB-contiguous runs per a. LDS 33 KB, aa-stride 516 floats
// (=16*32+4) so successive aa rows start 4 banks apart.
// ---------------------------------------------------------------------------
__global__ __launch_bounds__(256) void transpose_T(
    const float* __restrict__ Tws, float* __restrict__ out, int z0)
{
    __shared__ __align__(16) float lds[16 * 516];
    const int blk  = blockIdx.x;
    const int zrel = blk >> 8;
    const int z    = z0 + zrel;
    const int tile = blk & 255;
    const int a0   = (tile >> 4) << 4;
    const int b0   = (tile & 15) << 4;
    const int t    = threadIdx.x;
    const float* Tz = Tws + (size_t)zrel * N * NC;

#pragma unroll
    for (int q = 0; q < 8; ++q) {
        const int idx = q * 256 + t;     // 0..2047
        const int bb  = idx >> 7;
        const int pos = idx & 127;
        const int aa  = pos >> 3;
        const int i4  = pos & 7;
        const f4 v = __builtin_nontemporal_load(
            reinterpret_cast<const f4*>(
                &Tz[(size_t)(b0 + bb) * NC + (a0 + aa) * COUT + i4 * 4]));
        *reinterpret_cast<f4*>(&lds[aa * 516 + bb * 32 + i4 * 4]) = v;
    }
    __syncthreads();
#pragma unroll
    for (int q = 0; q < 8; ++q) {
        const int idx = q * 256 + t;
        const int aa  = idx >> 7;
        const int pos = idx & 127;
        const int bb  = pos >> 3;
        const int i4  = pos & 7;
        const f4 v = *reinterpret_cast<const f4*>(&lds[aa * 516 + bb * 32 + i4 * 4]);
        __builtin_nontemporal_store(v, reinterpret_cast<f4*>(
            &out[(((size_t)z * N + a0 + aa) * N + (b0 + bb)) * COUT + i4 * 4]));
    }
}

extern "C" void kernel_launch(void* const* d_in, const int* in_sizes, int n_in,
                              void* d_out, int out_size, void* d_ws, size_t ws_size,
                              hipStream_t stream) {
    const float* features = (const float*)d_in[0];
    const float* geometry = (const float*)d_in[1];
    const float* W1 = (const float*)d_in[2];
    const float* b1 = (const float*)d_in[3];
    const float* W2 = (const float*)d_in[4];
    const float* b2 = (const float*)d_in[5];
    float* out = (float*)d_out;
    float* Tws = (float*)d_ws;

    const size_t Tfull = (size_t)Z * N * NC * sizeof(float);   // 33.5 MB
    if (ws_size >= Tfull) {
        fused_pair_T<<<Z * N, 256, 0, stream>>>(features, geometry, W1, b1, W2, b2, Tws, 0);
        transpose_T<<<Z * 256, 256, 0, stream>>>(Tws, out, 0);
    } else {
        // per-z fallback: 8.4 MB ws footprint (R1-proven safe)
        for (int z = 0; z < Z; ++z) {
            fused_pair_T<<<N, 256, 0, stream>>>(features, geometry, W1, b1, W2, b2, Tws, z);
            transpose_T<<<256, 256, 0, stream>>>(Tws, out, z);
        }
    }
}

// Round 5
// 167.899 us; speedup vs baseline: 2.1722x; 2.1722x over previous
//
#include <hip/hip_runtime.h>
#include <cstddef>

namespace {
constexpr int Z    = 4;
constexpr int N    = 256;
constexpr int CIN  = 32;
constexpr int COUT = 32;
constexpr int HID  = 64;
constexpr int OC   = COUT * CIN;  // 1024
}

typedef float f4 __attribute__((ext_vector_type(4)));

// ---------------------------------------------------------------------------
// Kernel A: one block per b (handles all 4 z).
//   M[z][b][i][h] = sum_j W2[h][i*32+j] * f[z,b,j]
//   bf[z][b][i]   = sum_j b2[i*32+j]   * f[z,b,j]
// W2 read exactly once per block, line-complete: lanes are i-adjacent
// (128 B apart), 32 lanes tile one 4 KB W2 row. M staged in LDS and written
// out as 4 contiguous 8 KB runs (coalesced float4, NORMAL stores so the
// lines stay in this XCD's L2 for kernel B).
// XCD alignment: kernel B's block for (z,b) is blk=z*256+b -> XCD b%8;
// this kernel's block b is also XCD b%8 -> M reads in kernel B L2-hit.
// ---------------------------------------------------------------------------
__global__ __launch_bounds__(256) void precompute_M(
    const float* __restrict__ features,
    const float* __restrict__ W2,
    const float* __restrict__ b2,
    float* __restrict__ Mws,
    float* __restrict__ bfws)
{
    __shared__ __align__(16) float fl[4][CIN];      // f[z][j]
    __shared__ __align__(16) float Ms[4][32][68];   // M[z][i][h], i-stride 68 (f4-aligned)
    const int b = blockIdx.x;        // 0..255
    const int t = threadIdx.x;

    if (t < 128)
        fl[t >> 5][t & 31] = features[((size_t)(t >> 5) * N + b) * CIN + (t & 31)];
    __syncthreads();

    const int i  = t & 31;
    const int h0 = t >> 5;           // 0..7
#pragma unroll
    for (int p = 0; p < 8; ++p) {
        const int h = h0 + 8 * p;
        const float4* w2r = reinterpret_cast<const float4*>(
            W2 + (size_t)h * OC + i * CIN);
        float4 w[8];
#pragma unroll
        for (int q = 0; q < 8; ++q) w[q] = w2r[q];
#pragma unroll
        for (int z = 0; z < 4; ++z) {
            const float4* fz = reinterpret_cast<const float4*>(&fl[z][0]);
            float v = 0.f;
#pragma unroll
            for (int q = 0; q < 8; ++q) {
                const float4 f = fz[q];
                v += w[q].x * f.x + w[q].y * f.y + w[q].z * f.z + w[q].w * f.w;
            }
            Ms[z][i][h] = v;
        }
    }

    // bf (b2 is tiny, L2-hot after first block)
    if (t < 128) {
        const int z = t >> 5, ii = t & 31;
        const float4* b2r = reinterpret_cast<const float4*>(b2 + ii * CIN);
        const float4* fz  = reinterpret_cast<const float4*>(&fl[z][0]);
        float v = 0.f;
#pragma unroll
        for (int q = 0; q < 8; ++q) {
            const float4 bb = b2r[q];
            const float4 f  = fz[q];
            v += bb.x * f.x + bb.y * f.y + bb.z * f.z + bb.w * f.w;
        }
        bfws[((size_t)z * N + b) * COUT + ii] = v;
    }
    __syncthreads();

    // coalesced M write-out: per z an 8 KB contiguous run
#pragma unroll
    for (int w4 = 0; w4 < 8; ++w4) {
        const int idx = w4 * 256 + t;    // f4 index 0..2047
        const int z   = idx >> 9;
        const int rem = idx & 511;
        const int ii  = rem >> 4;
        const int h4  = rem & 15;
        const float4 v = *reinterpret_cast<const float4*>(&Ms[z][ii][h4 * 4]);
        reinterpret_cast<float4*>(
            Mws + (((size_t)z * N + b) * COUT + ii) * HID)[h4] = v;
    }
}

// ---------------------------------------------------------------------------
// Kernel B: one block per (z, b) — R1-proven structure (84 us), math verbatim.
//   H[a][h] = relu((g[z,b]-g[z,a]) @ W1 + b1)   (256 x 64, LDS, stride 68)
//   OUT[a][i] = sum_h H[a][h] * M[z,b,i,h] + bf[z,b,i]
// Changes vs R1: nt loads for M (read exactly once, should L2-hit from
// kernel A on the same XCD), nt stores for out (never re-read; keep L2
// clean for M/geometry).
// ---------------------------------------------------------------------------
__global__ __launch_bounds__(256, 2) void pair_contract(
    const float* __restrict__ geometry,
    const float* __restrict__ W1,
    const float* __restrict__ b1,
    const float* __restrict__ Mws,
    const float* __restrict__ bfws,
    float* __restrict__ out)
{
    __shared__ __align__(16) float Hs[N * 68];       // H[a][h]; reused as stage[a][i] stride 36
    __shared__ __align__(16) float Ml[COUT * HID];   // 8 KB, M[i][h]
    __shared__ __align__(16) float w1l[3 * HID];
    __shared__ __align__(16) float b1l[HID];
    __shared__ __align__(16) float bfl[COUT];

    const int blk = blockIdx.x;   // Z*N = 1024; XCD = blk%8 = b%8
    const int z = blk >> 8;
    const int b = blk & 255;
    const int t = threadIdx.x;

    if (t < HID) {
        w1l[t]           = W1[t];
        w1l[HID + t]     = W1[HID + t];
        w1l[2 * HID + t] = W1[2 * HID + t];
        b1l[t]           = b1[t];
    }
    if (t < COUT) bfl[t] = bfws[((size_t)z * N + b) * COUT + t];
    {
        const f4* Ms = reinterpret_cast<const f4*>(
            Mws + (size_t)(z * N + b) * (COUT * HID));
        f4* Ml4 = reinterpret_cast<f4*>(Ml);
        Ml4[t]       = __builtin_nontemporal_load(Ms + t);
        Ml4[t + 256] = __builtin_nontemporal_load(Ms + t + 256);
    }
    const float gbx = geometry[((size_t)z * N + b) * 3 + 0];
    const float gby = geometry[((size_t)z * N + b) * 3 + 1];
    const float gbz = geometry[((size_t)z * N + b) * 3 + 2];
    const float gax = geometry[((size_t)z * N + t) * 3 + 0];
    const float gay = geometry[((size_t)z * N + t) * 3 + 1];
    const float gaz = geometry[((size_t)z * N + t) * 3 + 2];
    const float dx = gbx - gax, dy = gby - gay, dz = gbz - gaz;  // g[b] - g[a]
    __syncthreads();

    // H row a = t, 64 h values, float4 LDS writes.
#pragma unroll
    for (int k = 0; k < HID; k += 4) {
        const float4 w0  = *reinterpret_cast<const float4*>(&w1l[k]);
        const float4 w1v = *reinterpret_cast<const float4*>(&w1l[HID + k]);
        const float4 w2v = *reinterpret_cast<const float4*>(&w1l[2 * HID + k]);
        const float4 bb  = *reinterpret_cast<const float4*>(&b1l[k]);
        float4 h;
        h.x = fmaxf(dx * w0.x + dy * w1v.x + dz * w2v.x + bb.x, 0.f);
        h.y = fmaxf(dx * w0.y + dy * w1v.y + dz * w2v.y + bb.y, 0.f);
        h.z = fmaxf(dx * w0.z + dy * w1v.z + dz * w2v.z + bb.z, 0.f);
        h.w = fmaxf(dx * w0.w + dy * w1v.w + dz * w2v.w + bb.w, 0.f);
        *reinterpret_cast<float4*>(&Hs[t * 68 + k]) = h;
    }
    __syncthreads();

    const int a_thr = t & 31;
    const int i_thr = t >> 5;     // 0..7
    float acc[8][4];
#pragma unroll
    for (int u = 0; u < 8; ++u)
#pragma unroll
        for (int v = 0; v < 4; ++v) acc[u][v] = bfl[i_thr * 4 + v];

#pragma unroll
    for (int k4 = 0; k4 < 16; ++k4) {
        float4 m[4];
#pragma unroll
        for (int v = 0; v < 4; ++v)
            m[v] = *reinterpret_cast<const float4*>(&Ml[(i_thr * 4 + v) * HID + k4 * 4]);
#pragma unroll
        for (int u = 0; u < 8; ++u) {
            const float4 h = *reinterpret_cast<const float4*>(
                &Hs[(a_thr + 32 * u) * 68 + k4 * 4]);
#pragma unroll
            for (int v = 0; v < 4; ++v)
                acc[u][v] += h.x * m[v].x + h.y * m[v].y + h.z * m[v].z + h.w * m[v].w;
        }
    }
    __syncthreads();

    // Stage OUT[a][i] in LDS (stride 36), then coalesced nt stores:
    // each a-row is a full 128 B line at ((z*N+a)*N+b)*32, written once.
#pragma unroll
    for (int u = 0; u < 8; ++u) {
        float4 o;
        o.x = acc[u][0]; o.y = acc[u][1]; o.z = acc[u][2]; o.w = acc[u][3];
        *reinterpret_cast<float4*>(&Hs[(a_thr + 32 * u) * 36 + i_thr * 4]) = o;
    }
    __syncthreads();

    const size_t out_zb = ((size_t)z * N) * N + b;
#pragma unroll
    for (int r = 0; r < 8; ++r) {
        const int c  = r * 256 + t;   // 0..2047
        const int a  = c >> 3;
        const int i4 = c & 7;
        const f4 val = *reinterpret_cast<const f4*>(&Hs[a * 36 + i4 * 4]);
        __builtin_nontemporal_store(val, reinterpret_cast<f4*>(
            &out[(out_zb + (size_t)a * N) * COUT + i4 * 4]));
    }
}

extern "C" void kernel_launch(void* const* d_in, const int* in_sizes, int n_in,
                              void* d_out, int out_size, void* d_ws, size_t ws_size,
                              hipStream_t stream) {
    const float* features = (const float*)d_in[0];
    const float* geometry = (const float*)d_in[1];
    const float* W1 = (const float*)d_in[2];
    const float* b1 = (const float*)d_in[3];
    const float* W2 = (const float*)d_in[4];
    const float* b2 = (const float*)d_in[5];
    float* out = (float*)d_out;

    float* Mws  = (float*)d_ws;                          // Z*N*COUT*HID = 2,097,152 floats
    float* bfws = Mws + (size_t)Z * N * COUT * HID;      // + Z*N*COUT   = 32,768 floats

    precompute_M<<<N, 256, 0, stream>>>(features, W2, b2, Mws, bfws);
    pair_contract<<<Z * N, 256, 0, stream>>>(geometry, W1, b1, Mws, bfws, out);
}